// Round 1
// baseline (1687.748 us; speedup 1.0000x reference)
//
#include <hip/hip_runtime.h>

#define NN 50000
#define NE 800000
#define NF 128
#define BF 16
#define NH 4
#define HC 128
#define CC 32
#define DEPTH 5
#define NEG 0.2f

// ---------------- CSR build ----------------
__global__ void k_count(const int* __restrict__ dst, int* __restrict__ deg) {
  int e = blockIdx.x * 256 + threadIdx.x;
  if (e < NE) atomicAdd(&deg[dst[e]], 1);
}

__global__ void k_partial(const int* __restrict__ deg, int* __restrict__ bsum) {
  __shared__ int s[256];
  int t = threadIdx.x;
  int i = blockIdx.x * 256 + t;
  s[t] = (i < NN) ? deg[i] : 0;
  __syncthreads();
  for (int d = 128; d > 0; d >>= 1) {
    if (t < d) s[t] += s[t + d];
    __syncthreads();
  }
  if (t == 0) bsum[blockIdx.x] = s[0];
}

__global__ void k_scan_top(int* __restrict__ bsum, int nb) {
  if (threadIdx.x == 0 && blockIdx.x == 0) {
    int run = 0;
    for (int i = 0; i < nb; ++i) { int v = bsum[i]; bsum[i] = run; run += v; }
  }
}

__global__ void k_scan_write(const int* __restrict__ deg, const int* __restrict__ bsum,
                             int* __restrict__ offs) {
  __shared__ int s[256];
  int t = threadIdx.x;
  int i = blockIdx.x * 256 + t;
  int v = (i < NN) ? deg[i] : 0;
  s[t] = v;
  __syncthreads();
  for (int d = 1; d < 256; d <<= 1) {
    int x = (t >= d) ? s[t - d] : 0;
    __syncthreads();
    s[t] += x;
    __syncthreads();
  }
  if (i < NN) offs[i] = bsum[blockIdx.x] + s[t] - v;
  if (i == 0) offs[NN] = NE;
}

__global__ void k_fill(const int* __restrict__ dst, const int* __restrict__ offs,
                       int* __restrict__ cur, int* __restrict__ csr) {
  int e = blockIdx.x * 256 + threadIdx.x;
  if (e < NE) {
    int d = dst[e];
    int p = atomicAdd(&cur[d], 1);
    csr[offs[d] + p] = e;
  }
}

// self-loop attr = mean of incoming edge_attr (deterministic CSR-order sum)
__global__ void k_slattr(const int* __restrict__ offs, const int* __restrict__ csr,
                         const float* __restrict__ eattr, float* __restrict__ sl) {
  int idx = blockIdx.x * 256 + threadIdx.x; // NN*BF
  if (idx >= NN * BF) return;
  int n = idx >> 4, f = idx & 15;
  int s = offs[n], e = offs[n + 1];
  float acc = 0.f;
  for (int i = s; i < e; ++i) acc += eattr[(size_t)csr[i] * BF + f];
  int cnt = e - s;
  sl[idx] = acc / fmaxf((float)cnt, 1.0f);
}

// ---------------- per-layer kernels ----------------
// xp = A @ W  (A: [NN,128], W: [128,128]); 16 rows/block, 2x4 register blocking
__global__ __launch_bounds__(256) void k_gemm(const float* __restrict__ A,
                                              const float* __restrict__ W,
                                              float* __restrict__ xp) {
  __shared__ float4 hs4[16 * 32]; // 16 rows x 128 cols = 8KB
  int t = threadIdx.x;
  int row0 = blockIdx.x * 16;
  for (int i = t; i < 16 * 32; i += 256) {
    int r = i >> 5;
    if (row0 + r < NN)
      hs4[i] = ((const float4*)A)[(size_t)(row0 + r) * 32 + (i & 31)];
    else
      hs4[i] = make_float4(0.f, 0.f, 0.f, 0.f);
  }
  __syncthreads();
  int tx = t & 31;  // cols tx*4..tx*4+3
  int ty = t >> 5;  // rows ty*2, ty*2+1
  float acc[2][4] = {};
  const float4* W4 = (const float4*)W;
  for (int k4 = 0; k4 < 32; ++k4) {
    float4 h0 = hs4[(ty * 2) * 32 + k4];
    float4 h1 = hs4[(ty * 2 + 1) * 32 + k4];
    float ha0[4] = {h0.x, h0.y, h0.z, h0.w};
    float ha1[4] = {h1.x, h1.y, h1.z, h1.w};
#pragma unroll
    for (int kk = 0; kk < 4; ++kk) {
      float4 w = W4[(size_t)(k4 * 4 + kk) * 32 + tx];
      float a0 = ha0[kk], a1 = ha1[kk];
      acc[0][0] += a0 * w.x; acc[0][1] += a0 * w.y; acc[0][2] += a0 * w.z; acc[0][3] += a0 * w.w;
      acc[1][0] += a1 * w.x; acc[1][1] += a1 * w.y; acc[1][2] += a1 * w.z; acc[1][3] += a1 * w.w;
    }
  }
#pragma unroll
  for (int r = 0; r < 2; ++r) {
    int row = row0 + ty * 2 + r;
    if (row < NN)
      ((float4*)xp)[(size_t)row * 32 + tx] = make_float4(acc[r][0], acc[r][1], acc[r][2], acc[r][3]);
  }
}

// a_s[n,h] = xp[n,h,:]·att_src[h,:]; a_d likewise
__global__ void k_asad(const float* __restrict__ xp, const float* __restrict__ as_w,
                       const float* __restrict__ ad_w, float* __restrict__ a_s,
                       float* __restrict__ a_d) {
  int idx = blockIdx.x * 256 + threadIdx.x;
  if (idx >= NN * NH) return;
  int n = idx >> 2, h = idx & 3;
  const float4* xr = (const float4*)(xp + (size_t)n * HC + h * CC);
  const float4* sw = (const float4*)(as_w + h * CC);
  const float4* dw = (const float4*)(ad_w + h * CC);
  float s = 0.f, d = 0.f;
#pragma unroll
  for (int i = 0; i < 8; ++i) {
    float4 x4 = xr[i], s4 = sw[i], d4 = dw[i];
    s += x4.x * s4.x + x4.y * s4.y + x4.z * s4.z + x4.w * s4.w;
    d += x4.x * d4.x + x4.y * d4.y + x4.z * d4.z + x4.w * d4.w;
  }
  a_s[idx] = s;
  a_d[idx] = d;
}

// alpha[e,h] = leaky_relu(a_s[src]+a_d[dst]+ea[e]·we_eff, 0.2) for e in [0, NE+NN)
__global__ __launch_bounds__(256) void k_alpha(const int* __restrict__ esrc, const int* __restrict__ edst,
                                               const float* __restrict__ eattr, const float* __restrict__ sl,
                                               const float* __restrict__ a_s, const float* __restrict__ a_d,
                                               const float* __restrict__ We_l, const float* __restrict__ ae_l,
                                               float* __restrict__ alpha) {
  __shared__ float weff[BF][NH];
  int t = threadIdx.x;
  if (t < BF * NH) {
    int f = t >> 2, h = t & 3;
    float acc = 0.f;
    for (int c = 0; c < CC; ++c) acc += We_l[f * HC + h * CC + c] * ae_l[h * CC + c];
    weff[f][h] = acc;
  }
  __syncthreads();
  int e = blockIdx.x * 256 + t;
  if (e >= NE + NN) return;
  int src, dst;
  const float* attr;
  if (e < NE) {
    src = esrc[e]; dst = edst[e]; attr = eattr + (size_t)e * BF;
  } else {
    src = dst = e - NE; attr = sl + (size_t)(e - NE) * BF;
  }
  float ae[NH] = {0.f, 0.f, 0.f, 0.f};
#pragma unroll
  for (int f = 0; f < BF; ++f) {
    float av = attr[f];
    ae[0] += av * weff[f][0]; ae[1] += av * weff[f][1];
    ae[2] += av * weff[f][2]; ae[3] += av * weff[f][3];
  }
  float4 sv = ((const float4*)a_s)[src];
  float4 dv = ((const float4*)a_d)[dst];
  float v0 = sv.x + dv.x + ae[0];
  float v1 = sv.y + dv.y + ae[1];
  float v2 = sv.z + dv.z + ae[2];
  float v3 = sv.w + dv.w + ae[3];
  float4 o;
  o.x = v0 > 0.f ? v0 : NEG * v0;
  o.y = v1 > 0.f ? v1 : NEG * v1;
  o.z = v2 > 0.f ? v2 : NEG * v2;
  o.w = v3 > 0.f ? v3 : NEG * v3;
  ((float4*)alpha)[e] = o;
}

// one wave per node: softmax over incoming edges (+self loop), aggregate xp[src]
__global__ __launch_bounds__(256) void k_aggr(const float* __restrict__ xp, const float* __restrict__ alpha,
                                              const int* __restrict__ csr, const int* __restrict__ offs,
                                              const int* __restrict__ esrc, const float* __restrict__ b_l,
                                              float* __restrict__ hout) {
  int node = blockIdx.x * 4 + (threadIdx.x >> 6);
  if (node >= NN) return;
  int lane = threadIdx.x & 63;
  int h1 = lane >> 5, h2 = h1 + 2;
  int ch1 = lane, ch2 = lane + 64;
  int s = offs[node], e = offs[node + 1];
  float aself1 = alpha[(size_t)(NE + node) * 4 + h1];
  float aself2 = alpha[(size_t)(NE + node) * 4 + h2];
  float m1 = aself1, m2 = aself2;
  for (int i = s; i < e; ++i) {
    int eid = csr[i];
    m1 = fmaxf(m1, alpha[(size_t)eid * 4 + h1]);
    m2 = fmaxf(m2, alpha[(size_t)eid * 4 + h2]);
  }
  float ex1 = __expf(aself1 - m1), ex2 = __expf(aself2 - m2);
  float den1 = ex1, den2 = ex2;
  float acc1 = ex1 * xp[(size_t)node * HC + ch1];
  float acc2 = ex2 * xp[(size_t)node * HC + ch2];
  for (int i = s; i < e; ++i) {
    int eid = csr[i];
    int sr = esrc[eid];
    float e1 = __expf(alpha[(size_t)eid * 4 + h1] - m1);
    float e2 = __expf(alpha[(size_t)eid * 4 + h2] - m2);
    den1 += e1; den2 += e2;
    acc1 += e1 * xp[(size_t)sr * HC + ch1];
    acc2 += e2 * xp[(size_t)sr * HC + ch2];
  }
  float o1 = acc1 / (den1 + 1e-16f) + b_l[ch1];
  float o2 = acc2 / (den2 + 1e-16f) + b_l[ch2];
  hout[(size_t)node * HC + ch1] = fmaxf(o1, 0.f);
  hout[(size_t)node * HC + ch2] = fmaxf(o2, 0.f);
}

// out = relu([x, h] @ Wout + bout)
__global__ void k_final(const float* __restrict__ x, const float* __restrict__ h,
                        const float* __restrict__ Wout, const float* __restrict__ bout,
                        float* __restrict__ out) {
  int idx = blockIdx.x * 256 + threadIdx.x;
  if (idx >= NN * CC) return;
  int n = idx >> 5, c = idx & 31;
  float acc = bout[c];
  const float* xr = x + (size_t)n * NF;
  const float* hr = h + (size_t)n * HC;
  for (int k = 0; k < NF; ++k) acc += xr[k] * Wout[k * CC + c];
  for (int k = 0; k < HC; ++k) acc += hr[k] * Wout[(NF + k) * CC + c];
  out[idx] = fmaxf(acc, 0.f);
}

extern "C" void kernel_launch(void* const* d_in, const int* in_sizes, int n_in,
                              void* d_out, int out_size, void* d_ws, size_t ws_size,
                              hipStream_t stream) {
  const float* x        = (const float*)d_in[0];
  const int*   eidx     = (const int*)d_in[1];
  const float* eattr    = (const float*)d_in[2];
  const float* W        = (const float*)d_in[3];
  const float* att_src  = (const float*)d_in[4];
  const float* att_dst  = (const float*)d_in[5];
  const float* We       = (const float*)d_in[6];
  const float* att_edge = (const float*)d_in[7];
  const float* b        = (const float*)d_in[8];
  const float* Wout     = (const float*)d_in[9];
  const float* bout     = (const float*)d_in[10];
  float* out = (float*)d_out;

  const int* esrc = eidx;
  const int* edst = eidx + NE;

  size_t off = 0;
  auto carve = [&](size_t bytes) {
    void* p = (char*)d_ws + off;
    off += (bytes + 255) & ~(size_t)255;
    return p;
  };
  float* h_buf = (float*)carve((size_t)NN * HC * 4);
  float* xp    = (float*)carve((size_t)NN * HC * 4);
  float* a_s   = (float*)carve((size_t)NN * NH * 4);
  float* a_d   = (float*)carve((size_t)NN * NH * 4);
  float* alpha = (float*)carve((size_t)(NE + NN) * NH * 4);
  float* sl    = (float*)carve((size_t)NN * BF * 4);
  int* deg  = (int*)carve((size_t)NN * 4);
  int* offs = (int*)carve((size_t)(NN + 1) * 4);
  int* cur  = (int*)carve((size_t)NN * 4);
  int* csr  = (int*)carve((size_t)NE * 4);
  int* bsum = (int*)carve(1024);

  const int nbN = (NN + 255) / 256;          // 196
  const int nbE = (NE + 255) / 256;
  const int nbEN = (NE + NN + 255) / 256;

  hipMemsetAsync(deg, 0, (size_t)NN * 4, stream);
  hipMemsetAsync(cur, 0, (size_t)NN * 4, stream);
  k_count<<<nbE, 256, 0, stream>>>(edst, deg);
  k_partial<<<nbN, 256, 0, stream>>>(deg, bsum);
  k_scan_top<<<1, 64, 0, stream>>>(bsum, nbN);
  k_scan_write<<<nbN, 256, 0, stream>>>(deg, bsum, offs);
  k_fill<<<nbE, 256, 0, stream>>>(edst, offs, cur, csr);
  k_slattr<<<(NN * BF + 255) / 256, 256, 0, stream>>>(offs, csr, eattr, sl);

  for (int l = 0; l < DEPTH; ++l) {
    const float* A = (l == 0) ? x : h_buf;
    k_gemm<<<(NN + 15) / 16, 256, 0, stream>>>(A, W + (size_t)l * NF * HC, xp);
    k_asad<<<(NN * NH + 255) / 256, 256, 0, stream>>>(xp, att_src + l * NH * CC,
                                                      att_dst + l * NH * CC, a_s, a_d);
    k_alpha<<<nbEN, 256, 0, stream>>>(esrc, edst, eattr, sl, a_s, a_d,
                                      We + (size_t)l * BF * HC, att_edge + l * NH * CC, alpha);
    k_aggr<<<(NN + 3) / 4, 256, 0, stream>>>(xp, alpha, csr, offs, esrc, b + l * HC, h_buf);
  }
  k_final<<<(NN * CC + 255) / 256, 256, 0, stream>>>(x, h_buf, Wout, bout, out);
}

// Round 2
// 864.295 us; speedup vs baseline: 1.9527x; 1.9527x over previous
//
#include <hip/hip_runtime.h>

#define NN 50000
#define NE 800000
#define NF 128
#define BF 16
#define NH 4
#define HC 128
#define CC 32
#define DEPTH 5
#define NEG 0.2f

__device__ inline unsigned short f2bf(float f) {
  union { float f; unsigned u; } v; v.f = f;
  unsigned r = v.u + 0x7fff + ((v.u >> 16) & 1);
  return (unsigned short)(r >> 16);
}
__device__ inline float bf2f(unsigned short u) {
  union { unsigned u; float f; } v; v.u = (unsigned)u << 16; return v.f;
}

// ---------------- CSR build ----------------
__global__ void k_count(const int* __restrict__ dst, int* __restrict__ deg) {
  int e = blockIdx.x * 256 + threadIdx.x;
  if (e < NE) atomicAdd(&deg[dst[e]], 1);
}

__global__ void k_partial(const int* __restrict__ deg, int* __restrict__ bsum) {
  __shared__ int s[256];
  int t = threadIdx.x;
  int i = blockIdx.x * 256 + t;
  s[t] = (i < NN) ? deg[i] : 0;
  __syncthreads();
  for (int d = 128; d > 0; d >>= 1) {
    if (t < d) s[t] += s[t + d];
    __syncthreads();
  }
  if (t == 0) bsum[blockIdx.x] = s[0];
}

__global__ void k_scan_top(int* __restrict__ bsum, int nb) {
  if (threadIdx.x == 0 && blockIdx.x == 0) {
    int run = 0;
    for (int i = 0; i < nb; ++i) { int v = bsum[i]; bsum[i] = run; run += v; }
  }
}

__global__ void k_scan_write(const int* __restrict__ deg, const int* __restrict__ bsum,
                             int* __restrict__ offs) {
  __shared__ int s[256];
  int t = threadIdx.x;
  int i = blockIdx.x * 256 + t;
  int v = (i < NN) ? deg[i] : 0;
  s[t] = v;
  __syncthreads();
  for (int d = 1; d < 256; d <<= 1) {
    int x = (t >= d) ? s[t - d] : 0;
    __syncthreads();
    s[t] += x;
    __syncthreads();
  }
  if (i < NN) offs[i] = bsum[blockIdx.x] + s[t] - v;
  if (i == 0) offs[NN] = NE;
}

// fill CSR: eid list (for slattr), src list (for aggr), pos[e] (for alpha scatter)
__global__ void k_fill(const int* __restrict__ src, const int* __restrict__ dst,
                       const int* __restrict__ offs, int* __restrict__ cur,
                       int* __restrict__ csr, int* __restrict__ src_csr,
                       int* __restrict__ pos) {
  int e = blockIdx.x * 256 + threadIdx.x;
  if (e < NE) {
    int d = dst[e];
    int p = atomicAdd(&cur[d], 1);
    int slot = offs[d] + p;
    csr[slot] = e;
    src_csr[slot] = src[e];
    pos[e] = slot;
  }
}

// self-loop attr = mean of incoming edge_attr
__global__ void k_slattr(const int* __restrict__ offs, const int* __restrict__ csr,
                         const float* __restrict__ eattr, float* __restrict__ sl) {
  int idx = blockIdx.x * 256 + threadIdx.x; // NN*BF
  if (idx >= NN * BF) return;
  int n = idx >> 4, f = idx & 15;
  int s = offs[n], e = offs[n + 1];
  float acc = 0.f;
  for (int i = s; i < e; ++i) acc += eattr[(size_t)csr[i] * BF + f];
  int cnt = e - s;
  sl[idx] = acc / fmaxf((float)cnt, 1.0f);
}

// ---------------- per-layer kernels ----------------
// xp = A @ W (bf16 out) + fused a_s/a_d epilogue.
// NN = 50000 = 16*3125, grid exact.
__global__ __launch_bounds__(256) void k_gemm(const float* __restrict__ A,
                                              const float* __restrict__ W,
                                              const float* __restrict__ as_w,
                                              const float* __restrict__ ad_w,
                                              unsigned short* __restrict__ xpb,
                                              float* __restrict__ a_s,
                                              float* __restrict__ a_d) {
  __shared__ float4 hs4[16 * 32]; // 16 rows x 128 cols = 8KB
  int t = threadIdx.x;
  int row0 = blockIdx.x * 16;
  for (int i = t; i < 16 * 32; i += 256) {
    int r = i >> 5;
    hs4[i] = ((const float4*)A)[(size_t)(row0 + r) * 32 + (i & 31)];
  }
  __syncthreads();
  int tx = t & 31;  // cols tx*4..tx*4+3
  int ty = t >> 5;  // rows ty*2, ty*2+1
  float acc[2][4] = {};
  const float4* W4 = (const float4*)W;
  for (int k4 = 0; k4 < 32; ++k4) {
    float4 h0 = hs4[(ty * 2) * 32 + k4];
    float4 h1 = hs4[(ty * 2 + 1) * 32 + k4];
    float ha0[4] = {h0.x, h0.y, h0.z, h0.w};
    float ha1[4] = {h1.x, h1.y, h1.z, h1.w};
#pragma unroll
    for (int kk = 0; kk < 4; ++kk) {
      float4 w = W4[(size_t)(k4 * 4 + kk) * 32 + tx];
      float a0 = ha0[kk], a1 = ha1[kk];
      acc[0][0] += a0 * w.x; acc[0][1] += a0 * w.y; acc[0][2] += a0 * w.z; acc[0][3] += a0 * w.w;
      acc[1][0] += a1 * w.x; acc[1][1] += a1 * w.y; acc[1][2] += a1 * w.z; acc[1][3] += a1 * w.w;
    }
  }
  float4 as4 = ((const float4*)as_w)[tx];
  float4 ad4 = ((const float4*)ad_w)[tx];
#pragma unroll
  for (int r = 0; r < 2; ++r) {
    int row = row0 + ty * 2 + r;
    ushort4 u;
    u.x = f2bf(acc[r][0]); u.y = f2bf(acc[r][1]);
    u.z = f2bf(acc[r][2]); u.w = f2bf(acc[r][3]);
    ((ushort4*)xpb)[(size_t)row * 32 + tx] = u;
    float ps = acc[r][0] * as4.x + acc[r][1] * as4.y + acc[r][2] * as4.z + acc[r][3] * as4.w;
    float pd = acc[r][0] * ad4.x + acc[r][1] * ad4.y + acc[r][2] * ad4.z + acc[r][3] * ad4.w;
    // reduce across the 8 lanes sharing a head (tx>>3)
    ps += __shfl_xor(ps, 1); pd += __shfl_xor(pd, 1);
    ps += __shfl_xor(ps, 2); pd += __shfl_xor(pd, 2);
    ps += __shfl_xor(ps, 4); pd += __shfl_xor(pd, 4);
    if ((tx & 7) == 0) {
      a_s[(size_t)row * 4 + (tx >> 3)] = ps;
      a_d[(size_t)row * 4 + (tx >> 3)] = pd;
    }
  }
}

// alpha = leaky_relu(a_s[src]+a_d[dst]+ea·we_eff); scatter into CSR order.
__global__ __launch_bounds__(256) void k_alpha(const int* __restrict__ esrc, const int* __restrict__ edst,
                                               const float* __restrict__ eattr, const float* __restrict__ sl,
                                               const float* __restrict__ a_s, const float* __restrict__ a_d,
                                               const float* __restrict__ We_l, const float* __restrict__ ae_l,
                                               const int* __restrict__ pos,
                                               float* __restrict__ alpha_csr,
                                               float* __restrict__ alpha_self) {
  __shared__ float weff[BF][NH];
  int t = threadIdx.x;
  if (t < BF * NH) {
    int f = t >> 2, h = t & 3;
    float acc = 0.f;
    for (int c = 0; c < CC; ++c) acc += We_l[f * HC + h * CC + c] * ae_l[h * CC + c];
    weff[f][h] = acc;
  }
  __syncthreads();
  int e = blockIdx.x * 256 + t;
  if (e >= NE + NN) return;
  int src, dst;
  const float* attr;
  if (e < NE) {
    src = esrc[e]; dst = edst[e]; attr = eattr + (size_t)e * BF;
  } else {
    src = dst = e - NE; attr = sl + (size_t)(e - NE) * BF;
  }
  float ae[NH] = {0.f, 0.f, 0.f, 0.f};
#pragma unroll
  for (int f = 0; f < BF; ++f) {
    float av = attr[f];
    ae[0] += av * weff[f][0]; ae[1] += av * weff[f][1];
    ae[2] += av * weff[f][2]; ae[3] += av * weff[f][3];
  }
  float4 sv = ((const float4*)a_s)[src];
  float4 dv = ((const float4*)a_d)[dst];
  float v0 = sv.x + dv.x + ae[0];
  float v1 = sv.y + dv.y + ae[1];
  float v2 = sv.z + dv.z + ae[2];
  float v3 = sv.w + dv.w + ae[3];
  float4 o;
  o.x = v0 > 0.f ? v0 : NEG * v0;
  o.y = v1 > 0.f ? v1 : NEG * v1;
  o.z = v2 > 0.f ? v2 : NEG * v2;
  o.w = v3 > 0.f ? v3 : NEG * v3;
  if (e < NE)
    ((float4*)alpha_csr)[pos[e]] = o;
  else
    ((float4*)alpha_self)[e - NE] = o;
}

// one wave per node: online softmax + aggregate (bf16 xp gather), streamed CSR.
// lane owns channels {2*lane, 2*lane+1}; head = lane>>4.
__global__ __launch_bounds__(256) void k_aggr(const unsigned short* __restrict__ xpb,
                                              const float* __restrict__ alpha_csr,
                                              const float* __restrict__ alpha_self,
                                              const int* __restrict__ src_csr,
                                              const int* __restrict__ offs,
                                              const float* __restrict__ b_l,
                                              float* __restrict__ hout) {
  int node = blockIdx.x * 4 + (threadIdx.x >> 6);
  if (node >= NN) return;
  int lane = threadIdx.x & 63;
  int h = lane >> 4;
  const ushort2* xp2 = (const ushort2*)xpb;
  int s = offs[node], e = offs[node + 1];
  float m = alpha_self[(size_t)node * 4 + h];
  ushort2 xs = xp2[(size_t)node * 64 + lane];
  float acc0 = bf2f(xs.x), acc1 = bf2f(xs.y);  // self weight exp(a_self - m) = 1
  float den = 1.f;
  int i = s;
  for (; i + 4 <= e; i += 4) {
    int s0 = src_csr[i], s1 = src_csr[i + 1], s2 = src_csr[i + 2], s3 = src_csr[i + 3];
    float a0 = alpha_csr[(size_t)i * 4 + h];
    float a1 = alpha_csr[(size_t)(i + 1) * 4 + h];
    float a2 = alpha_csr[(size_t)(i + 2) * 4 + h];
    float a3 = alpha_csr[(size_t)(i + 3) * 4 + h];
    ushort2 x0 = xp2[(size_t)s0 * 64 + lane];
    ushort2 x1 = xp2[(size_t)s1 * 64 + lane];
    ushort2 x2 = xp2[(size_t)s2 * 64 + lane];
    ushort2 x3 = xp2[(size_t)s3 * 64 + lane];
    float mn = fmaxf(fmaxf(fmaxf(a0, a1), fmaxf(a2, a3)), m);
    float sc = __expf(m - mn);
    acc0 *= sc; acc1 *= sc; den *= sc; m = mn;
    float e0 = __expf(a0 - m), e1 = __expf(a1 - m), e2 = __expf(a2 - m), e3 = __expf(a3 - m);
    den += e0 + e1 + e2 + e3;
    acc0 += e0 * bf2f(x0.x) + e1 * bf2f(x1.x) + e2 * bf2f(x2.x) + e3 * bf2f(x3.x);
    acc1 += e0 * bf2f(x0.y) + e1 * bf2f(x1.y) + e2 * bf2f(x2.y) + e3 * bf2f(x3.y);
  }
  for (; i < e; ++i) {
    int s0 = src_csr[i];
    float a0 = alpha_csr[(size_t)i * 4 + h];
    ushort2 x0 = xp2[(size_t)s0 * 64 + lane];
    if (a0 > m) { float sc = __expf(m - a0); acc0 *= sc; acc1 *= sc; den *= sc; m = a0; }
    float e0 = __expf(a0 - m);
    den += e0;
    acc0 += e0 * bf2f(x0.x);
    acc1 += e0 * bf2f(x0.y);
  }
  float2 b2 = ((const float2*)b_l)[lane];
  float inv = 1.0f / (den + 1e-16f);
  float o0 = acc0 * inv + b2.x;
  float o1 = acc1 * inv + b2.y;
  ((float2*)hout)[(size_t)node * 64 + lane] = make_float2(fmaxf(o0, 0.f), fmaxf(o1, 0.f));
}

// out = relu([x, h] @ Wout + bout)
__global__ void k_final(const float* __restrict__ x, const float* __restrict__ h,
                        const float* __restrict__ Wout, const float* __restrict__ bout,
                        float* __restrict__ out) {
  int idx = blockIdx.x * 256 + threadIdx.x;
  if (idx >= NN * CC) return;
  int n = idx >> 5, c = idx & 31;
  float acc = bout[c];
  const float* xr = x + (size_t)n * NF;
  const float* hr = h + (size_t)n * HC;
  for (int k = 0; k < NF; ++k) acc += xr[k] * Wout[k * CC + c];
  for (int k = 0; k < HC; ++k) acc += hr[k] * Wout[(NF + k) * CC + c];
  out[idx] = fmaxf(acc, 0.f);
}

extern "C" void kernel_launch(void* const* d_in, const int* in_sizes, int n_in,
                              void* d_out, int out_size, void* d_ws, size_t ws_size,
                              hipStream_t stream) {
  const float* x        = (const float*)d_in[0];
  const int*   eidx     = (const int*)d_in[1];
  const float* eattr    = (const float*)d_in[2];
  const float* W        = (const float*)d_in[3];
  const float* att_src  = (const float*)d_in[4];
  const float* att_dst  = (const float*)d_in[5];
  const float* We       = (const float*)d_in[6];
  const float* att_edge = (const float*)d_in[7];
  const float* b        = (const float*)d_in[8];
  const float* Wout     = (const float*)d_in[9];
  const float* bout     = (const float*)d_in[10];
  float* out = (float*)d_out;

  const int* esrc = eidx;
  const int* edst = eidx + NE;

  size_t off = 0;
  auto carve = [&](size_t bytes) {
    void* p = (char*)d_ws + off;
    off += (bytes + 255) & ~(size_t)255;
    return p;
  };
  float* h_buf  = (float*)carve((size_t)NN * HC * 4);
  unsigned short* xpb = (unsigned short*)carve((size_t)NN * HC * 2);
  float* a_s    = (float*)carve((size_t)NN * NH * 4);
  float* a_d    = (float*)carve((size_t)NN * NH * 4);
  float* alpha_csr  = (float*)carve((size_t)NE * NH * 4);
  float* alpha_self = (float*)carve((size_t)NN * NH * 4);
  float* sl     = (float*)carve((size_t)NN * BF * 4);
  int* deg  = (int*)carve((size_t)NN * 4);
  int* offs = (int*)carve((size_t)(NN + 1) * 4);
  int* cur  = (int*)carve((size_t)NN * 4);
  int* csr  = (int*)carve((size_t)NE * 4);
  int* src_csr = (int*)carve((size_t)NE * 4);
  int* pos  = (int*)carve((size_t)NE * 4);
  int* bsum = (int*)carve(1024);

  const int nbN = (NN + 255) / 256;
  const int nbE = (NE + 255) / 256;
  const int nbEN = (NE + NN + 255) / 256;

  hipMemsetAsync(deg, 0, (size_t)NN * 4, stream);
  hipMemsetAsync(cur, 0, (size_t)NN * 4, stream);
  k_count<<<nbE, 256, 0, stream>>>(edst, deg);
  k_partial<<<nbN, 256, 0, stream>>>(deg, bsum);
  k_scan_top<<<1, 64, 0, stream>>>(bsum, nbN);
  k_scan_write<<<nbN, 256, 0, stream>>>(deg, bsum, offs);
  k_fill<<<nbE, 256, 0, stream>>>(esrc, edst, offs, cur, csr, src_csr, pos);
  k_slattr<<<(NN * BF + 255) / 256, 256, 0, stream>>>(offs, csr, eattr, sl);

  for (int l = 0; l < DEPTH; ++l) {
    const float* A = (l == 0) ? x : h_buf;
    k_gemm<<<NN / 16, 256, 0, stream>>>(A, W + (size_t)l * NF * HC,
                                        att_src + (size_t)l * NH * CC,
                                        att_dst + (size_t)l * NH * CC,
                                        xpb, a_s, a_d);
    k_alpha<<<nbEN, 256, 0, stream>>>(esrc, edst, eattr, sl, a_s, a_d,
                                      We + (size_t)l * BF * HC,
                                      att_edge + (size_t)l * NH * CC,
                                      pos, alpha_csr, alpha_self);
    k_aggr<<<(NN + 3) / 4, 256, 0, stream>>>(xpb, alpha_csr, alpha_self,
                                             src_csr, offs, b + (size_t)l * HC, h_buf);
  }
  k_final<<<(NN * CC + 255) / 256, 256, 0, stream>>>(x, h_buf, Wout, bout, out);
}

// Round 3
// 809.661 us; speedup vs baseline: 2.0845x; 1.0675x over previous
//
#include <hip/hip_runtime.h>

#define NN 50000
#define NE 800000
#define NF 128
#define BF 16
#define NH 4
#define HC 128
#define CC 32
#define DEPTH 5
#define NEG 0.2f

__device__ inline unsigned short f2bf(float f) {
  union { float f; unsigned u; } v; v.f = f;
  unsigned r = v.u + 0x7fff + ((v.u >> 16) & 1);
  return (unsigned short)(r >> 16);
}
__device__ inline float bf2f(unsigned short u) {
  union { unsigned u; float f; } v; v.u = (unsigned)u << 16; return v.f;
}

// ---------------- CSR build ----------------
__global__ void k_count(const int* __restrict__ dst, int* __restrict__ deg) {
  int e = blockIdx.x * 256 + threadIdx.x;
  if (e < NE) atomicAdd(&deg[dst[e]], 1);
}

__global__ void k_partial(const int* __restrict__ deg, int* __restrict__ bsum) {
  __shared__ int s[256];
  int t = threadIdx.x;
  int i = blockIdx.x * 256 + t;
  s[t] = (i < NN) ? deg[i] : 0;
  __syncthreads();
  for (int d = 128; d > 0; d >>= 1) {
    if (t < d) s[t] += s[t + d];
    __syncthreads();
  }
  if (t == 0) bsum[blockIdx.x] = s[0];
}

__global__ void k_scan_top(int* __restrict__ bsum, int nb) {
  if (threadIdx.x == 0 && blockIdx.x == 0) {
    int run = 0;
    for (int i = 0; i < nb; ++i) { int v = bsum[i]; bsum[i] = run; run += v; }
  }
}

__global__ void k_scan_write(const int* __restrict__ deg, const int* __restrict__ bsum,
                             int* __restrict__ offs) {
  __shared__ int s[256];
  int t = threadIdx.x;
  int i = blockIdx.x * 256 + t;
  int v = (i < NN) ? deg[i] : 0;
  s[t] = v;
  __syncthreads();
  for (int d = 1; d < 256; d <<= 1) {
    int x = (t >= d) ? s[t - d] : 0;
    __syncthreads();
    s[t] += x;
    __syncthreads();
  }
  if (i < NN) offs[i] = bsum[blockIdx.x] + s[t] - v;
  if (i == 0) offs[NN] = NE;
}

// fill CSR: eid list (for slattr), src list (for aggr), pos[e] (for alpha scatter)
__global__ void k_fill(const int* __restrict__ src, const int* __restrict__ dst,
                       const int* __restrict__ offs, int* __restrict__ cur,
                       int* __restrict__ csr, int* __restrict__ src_csr,
                       int* __restrict__ pos) {
  int e = blockIdx.x * 256 + threadIdx.x;
  if (e < NE) {
    int d = dst[e];
    int p = atomicAdd(&cur[d], 1);
    int slot = offs[d] + p;
    csr[slot] = e;
    src_csr[slot] = src[e];
    pos[e] = slot;
  }
}

// self-loop attr = mean of incoming edge_attr
__global__ void k_slattr(const int* __restrict__ offs, const int* __restrict__ csr,
                         const float* __restrict__ eattr, float* __restrict__ sl) {
  int idx = blockIdx.x * 256 + threadIdx.x; // NN*BF
  if (idx >= NN * BF) return;
  int n = idx >> 4, f = idx & 15;
  int s = offs[n], e = offs[n + 1];
  float acc = 0.f;
  for (int i = s; i < e; ++i) acc += eattr[(size_t)csr[i] * BF + f];
  int cnt = e - s;
  sl[idx] = acc / fmaxf((float)cnt, 1.0f);
}

// ---------------- per-layer kernels ----------------
// xp = A @ W (bf16 out) + fused a_s/a_d epilogue. NN = 50000 = 16*3125.
__global__ __launch_bounds__(256) void k_gemm(const float* __restrict__ A,
                                              const float* __restrict__ W,
                                              const float* __restrict__ as_w,
                                              const float* __restrict__ ad_w,
                                              unsigned short* __restrict__ xpb,
                                              float* __restrict__ a_s,
                                              float* __restrict__ a_d) {
  __shared__ float4 hs4[16 * 32]; // 16 rows x 128 cols = 8KB
  int t = threadIdx.x;
  int row0 = blockIdx.x * 16;
  for (int i = t; i < 16 * 32; i += 256) {
    int r = i >> 5;
    hs4[i] = ((const float4*)A)[(size_t)(row0 + r) * 32 + (i & 31)];
  }
  __syncthreads();
  int tx = t & 31;  // cols tx*4..tx*4+3
  int ty = t >> 5;  // rows ty*2, ty*2+1
  float acc[2][4] = {};
  const float4* W4 = (const float4*)W;
  for (int k4 = 0; k4 < 32; ++k4) {
    float4 h0 = hs4[(ty * 2) * 32 + k4];
    float4 h1 = hs4[(ty * 2 + 1) * 32 + k4];
    float ha0[4] = {h0.x, h0.y, h0.z, h0.w};
    float ha1[4] = {h1.x, h1.y, h1.z, h1.w};
#pragma unroll
    for (int kk = 0; kk < 4; ++kk) {
      float4 w = W4[(size_t)(k4 * 4 + kk) * 32 + tx];
      float a0 = ha0[kk], a1 = ha1[kk];
      acc[0][0] += a0 * w.x; acc[0][1] += a0 * w.y; acc[0][2] += a0 * w.z; acc[0][3] += a0 * w.w;
      acc[1][0] += a1 * w.x; acc[1][1] += a1 * w.y; acc[1][2] += a1 * w.z; acc[1][3] += a1 * w.w;
    }
  }
  float4 as4 = ((const float4*)as_w)[tx];
  float4 ad4 = ((const float4*)ad_w)[tx];
#pragma unroll
  for (int r = 0; r < 2; ++r) {
    int row = row0 + ty * 2 + r;
    ushort4 u;
    u.x = f2bf(acc[r][0]); u.y = f2bf(acc[r][1]);
    u.z = f2bf(acc[r][2]); u.w = f2bf(acc[r][3]);
    ((ushort4*)xpb)[(size_t)row * 32 + tx] = u;
    float ps = acc[r][0] * as4.x + acc[r][1] * as4.y + acc[r][2] * as4.z + acc[r][3] * as4.w;
    float pd = acc[r][0] * ad4.x + acc[r][1] * ad4.y + acc[r][2] * ad4.z + acc[r][3] * ad4.w;
    ps += __shfl_xor(ps, 1); pd += __shfl_xor(pd, 1);
    ps += __shfl_xor(ps, 2); pd += __shfl_xor(pd, 2);
    ps += __shfl_xor(ps, 4); pd += __shfl_xor(pd, 4);
    if ((tx & 7) == 0) {
      a_s[(size_t)row * 4 + (tx >> 3)] = ps;
      a_d[(size_t)row * 4 + (tx >> 3)] = pd;
    }
  }
}

// alpha = leaky_relu(a_s[src]+a_d[dst]+ea·we_eff); scatter into CSR order.
__global__ __launch_bounds__(256) void k_alpha(const int* __restrict__ esrc, const int* __restrict__ edst,
                                               const float* __restrict__ eattr, const float* __restrict__ sl,
                                               const float* __restrict__ a_s, const float* __restrict__ a_d,
                                               const float* __restrict__ We_l, const float* __restrict__ ae_l,
                                               const int* __restrict__ pos,
                                               float* __restrict__ alpha_csr,
                                               float* __restrict__ alpha_self) {
  __shared__ float weff[BF][NH];
  int t = threadIdx.x;
  if (t < BF * NH) {
    int f = t >> 2, h = t & 3;
    float acc = 0.f;
    for (int c = 0; c < CC; ++c) acc += We_l[f * HC + h * CC + c] * ae_l[h * CC + c];
    weff[f][h] = acc;
  }
  __syncthreads();
  int e = blockIdx.x * 256 + t;
  if (e >= NE + NN) return;
  int src, dst;
  const float* attr;
  if (e < NE) {
    src = esrc[e]; dst = edst[e]; attr = eattr + (size_t)e * BF;
  } else {
    src = dst = e - NE; attr = sl + (size_t)(e - NE) * BF;
  }
  float ae[NH] = {0.f, 0.f, 0.f, 0.f};
#pragma unroll
  for (int f = 0; f < BF; ++f) {
    float av = attr[f];
    ae[0] += av * weff[f][0]; ae[1] += av * weff[f][1];
    ae[2] += av * weff[f][2]; ae[3] += av * weff[f][3];
  }
  float4 sv = ((const float4*)a_s)[src];
  float4 dv = ((const float4*)a_d)[dst];
  float v0 = sv.x + dv.x + ae[0];
  float v1 = sv.y + dv.y + ae[1];
  float v2 = sv.z + dv.z + ae[2];
  float v3 = sv.w + dv.w + ae[3];
  float4 o;
  o.x = v0 > 0.f ? v0 : NEG * v0;
  o.y = v1 > 0.f ? v1 : NEG * v1;
  o.z = v2 > 0.f ? v2 : NEG * v2;
  o.w = v3 > 0.f ? v3 : NEG * v3;
  if (e < NE)
    ((float4*)alpha_csr)[pos[e]] = o;
  else
    ((float4*)alpha_self)[e - NE] = o;
}

// one wave per node: online softmax + aggregate (bf16 xp gather), streamed CSR.
__global__ __launch_bounds__(256) void k_aggr(const unsigned short* __restrict__ xpb,
                                              const float* __restrict__ alpha_csr,
                                              const float* __restrict__ alpha_self,
                                              const int* __restrict__ src_csr,
                                              const int* __restrict__ offs,
                                              const float* __restrict__ b_l,
                                              float* __restrict__ hout) {
  int node = blockIdx.x * 4 + (threadIdx.x >> 6);
  if (node >= NN) return;
  int lane = threadIdx.x & 63;
  int h = lane >> 4;
  const ushort2* xp2 = (const ushort2*)xpb;
  int s = offs[node], e = offs[node + 1];
  float m = alpha_self[(size_t)node * 4 + h];
  ushort2 xs = xp2[(size_t)node * 64 + lane];
  float acc0 = bf2f(xs.x), acc1 = bf2f(xs.y);
  float den = 1.f;
  int i = s;
  for (; i + 4 <= e; i += 4) {
    int s0 = src_csr[i], s1 = src_csr[i + 1], s2 = src_csr[i + 2], s3 = src_csr[i + 3];
    float a0 = alpha_csr[(size_t)i * 4 + h];
    float a1 = alpha_csr[(size_t)(i + 1) * 4 + h];
    float a2 = alpha_csr[(size_t)(i + 2) * 4 + h];
    float a3 = alpha_csr[(size_t)(i + 3) * 4 + h];
    ushort2 x0 = xp2[(size_t)s0 * 64 + lane];
    ushort2 x1 = xp2[(size_t)s1 * 64 + lane];
    ushort2 x2 = xp2[(size_t)s2 * 64 + lane];
    ushort2 x3 = xp2[(size_t)s3 * 64 + lane];
    float mn = fmaxf(fmaxf(fmaxf(a0, a1), fmaxf(a2, a3)), m);
    float sc = __expf(m - mn);
    acc0 *= sc; acc1 *= sc; den *= sc; m = mn;
    float e0 = __expf(a0 - m), e1 = __expf(a1 - m), e2 = __expf(a2 - m), e3 = __expf(a3 - m);
    den += e0 + e1 + e2 + e3;
    acc0 += e0 * bf2f(x0.x) + e1 * bf2f(x1.x) + e2 * bf2f(x2.x) + e3 * bf2f(x3.x);
    acc1 += e0 * bf2f(x0.y) + e1 * bf2f(x1.y) + e2 * bf2f(x2.y) + e3 * bf2f(x3.y);
  }
  for (; i < e; ++i) {
    int s0 = src_csr[i];
    float a0 = alpha_csr[(size_t)i * 4 + h];
    ushort2 x0 = xp2[(size_t)s0 * 64 + lane];
    if (a0 > m) { float sc = __expf(m - a0); acc0 *= sc; acc1 *= sc; den *= sc; m = a0; }
    float e0 = __expf(a0 - m);
    den += e0;
    acc0 += e0 * bf2f(x0.x);
    acc1 += e0 * bf2f(x0.y);
  }
  float2 b2 = ((const float2*)b_l)[lane];
  float inv = 1.0f / (den + 1e-16f);
  float o0 = acc0 * inv + b2.x;
  float o1 = acc1 * inv + b2.y;
  ((float2*)hout)[(size_t)node * 64 + lane] = make_float2(fmaxf(o0, 0.f), fmaxf(o1, 0.f));
}

// out = relu([x, h] @ Wout + bout) — LDS-staged Wout, 64 nodes/block, float4.
__global__ __launch_bounds__(256) void k_final(const float* __restrict__ x, const float* __restrict__ h,
                                               const float* __restrict__ Wout, const float* __restrict__ bout,
                                               float* __restrict__ out) {
  __shared__ float4 wlds[2048]; // 256 x 32 fp32 = 32KB
  int t = threadIdx.x;
#pragma unroll
  for (int i = 0; i < 8; ++i) wlds[t + i * 256] = ((const float4*)Wout)[t + i * 256];
  __syncthreads();
  int tx = t & 7;   // col quad: cols tx*4..tx*4+3
  int ty = t >> 3;  // node within block (0..31); also handles ty+32
  int row0 = blockIdx.x * 64 + ty;
  int row1 = row0 + 32;
  bool v0 = row0 < NN, v1 = row1 < NN;
  const float4* x4 = (const float4*)x;
  const float4* h4 = (const float4*)h;
  float acc[2][4] = {};
  const float4 z = make_float4(0.f, 0.f, 0.f, 0.f);
#pragma unroll 4
  for (int k4 = 0; k4 < 32; ++k4) {
    float4 a0 = v0 ? x4[(size_t)row0 * 32 + k4] : z;
    float4 a1 = v1 ? x4[(size_t)row1 * 32 + k4] : z;
    float av0[4] = {a0.x, a0.y, a0.z, a0.w};
    float av1[4] = {a1.x, a1.y, a1.z, a1.w};
#pragma unroll
    for (int kk = 0; kk < 4; ++kk) {
      float4 w = wlds[(k4 * 4 + kk) * 8 + tx];
      acc[0][0] += av0[kk] * w.x; acc[0][1] += av0[kk] * w.y;
      acc[0][2] += av0[kk] * w.z; acc[0][3] += av0[kk] * w.w;
      acc[1][0] += av1[kk] * w.x; acc[1][1] += av1[kk] * w.y;
      acc[1][2] += av1[kk] * w.z; acc[1][3] += av1[kk] * w.w;
    }
  }
#pragma unroll 4
  for (int k4 = 0; k4 < 32; ++k4) {
    float4 a0 = v0 ? h4[(size_t)row0 * 32 + k4] : z;
    float4 a1 = v1 ? h4[(size_t)row1 * 32 + k4] : z;
    float av0[4] = {a0.x, a0.y, a0.z, a0.w};
    float av1[4] = {a1.x, a1.y, a1.z, a1.w};
#pragma unroll
    for (int kk = 0; kk < 4; ++kk) {
      float4 w = wlds[(128 + k4 * 4 + kk) * 8 + tx];
      acc[0][0] += av0[kk] * w.x; acc[0][1] += av0[kk] * w.y;
      acc[0][2] += av0[kk] * w.z; acc[0][3] += av0[kk] * w.w;
      acc[1][0] += av1[kk] * w.x; acc[1][1] += av1[kk] * w.y;
      acc[1][2] += av1[kk] * w.z; acc[1][3] += av1[kk] * w.w;
    }
  }
  float4 b4 = ((const float4*)bout)[tx];
  if (v0) {
    float4 o = make_float4(fmaxf(acc[0][0] + b4.x, 0.f), fmaxf(acc[0][1] + b4.y, 0.f),
                           fmaxf(acc[0][2] + b4.z, 0.f), fmaxf(acc[0][3] + b4.w, 0.f));
    ((float4*)out)[(size_t)row0 * 8 + tx] = o;
  }
  if (v1) {
    float4 o = make_float4(fmaxf(acc[1][0] + b4.x, 0.f), fmaxf(acc[1][1] + b4.y, 0.f),
                           fmaxf(acc[1][2] + b4.z, 0.f), fmaxf(acc[1][3] + b4.w, 0.f));
    ((float4*)out)[(size_t)row1 * 8 + tx] = o;
  }
}

extern "C" void kernel_launch(void* const* d_in, const int* in_sizes, int n_in,
                              void* d_out, int out_size, void* d_ws, size_t ws_size,
                              hipStream_t stream) {
  const float* x        = (const float*)d_in[0];
  const int*   eidx     = (const int*)d_in[1];
  const float* eattr    = (const float*)d_in[2];
  const float* W        = (const float*)d_in[3];
  const float* att_src  = (const float*)d_in[4];
  const float* att_dst  = (const float*)d_in[5];
  const float* We       = (const float*)d_in[6];
  const float* att_edge = (const float*)d_in[7];
  const float* b        = (const float*)d_in[8];
  const float* Wout     = (const float*)d_in[9];
  const float* bout     = (const float*)d_in[10];
  float* out = (float*)d_out;

  const int* esrc = eidx;
  const int* edst = eidx + NE;

  size_t off = 0;
  auto carve = [&](size_t bytes) {
    void* p = (char*)d_ws + off;
    off += (bytes + 255) & ~(size_t)255;
    return p;
  };
  float* h_buf  = (float*)carve((size_t)NN * HC * 4);
  unsigned short* xpb = (unsigned short*)carve((size_t)NN * HC * 2);
  float* a_s    = (float*)carve((size_t)NN * NH * 4);
  float* a_d    = (float*)carve((size_t)NN * NH * 4);
  float* alpha_csr  = (float*)carve((size_t)NE * NH * 4);
  float* alpha_self = (float*)carve((size_t)NN * NH * 4);
  float* sl     = (float*)carve((size_t)NN * BF * 4);
  int* deg  = (int*)carve((size_t)NN * 4);
  int* offs = (int*)carve((size_t)(NN + 1) * 4);
  int* cur  = (int*)carve((size_t)NN * 4);
  int* csr  = (int*)carve((size_t)NE * 4);
  int* src_csr = (int*)carve((size_t)NE * 4);
  int* pos  = (int*)carve((size_t)NE * 4);
  int* bsum = (int*)carve(1024);

  const int nbN = (NN + 255) / 256;
  const int nbE = (NE + 255) / 256;
  const int nbEN = (NE + NN + 255) / 256;

  hipMemsetAsync(deg, 0, (size_t)NN * 4, stream);
  hipMemsetAsync(cur, 0, (size_t)NN * 4, stream);
  k_count<<<nbE, 256, 0, stream>>>(edst, deg);
  k_partial<<<nbN, 256, 0, stream>>>(deg, bsum);
  k_scan_top<<<1, 64, 0, stream>>>(bsum, nbN);
  k_scan_write<<<nbN, 256, 0, stream>>>(deg, bsum, offs);
  k_fill<<<nbE, 256, 0, stream>>>(esrc, edst, offs, cur, csr, src_csr, pos);
  k_slattr<<<(NN * BF + 255) / 256, 256, 0, stream>>>(offs, csr, eattr, sl);

  for (int l = 0; l < DEPTH; ++l) {
    const float* A = (l == 0) ? x : h_buf;
    k_gemm<<<NN / 16, 256, 0, stream>>>(A, W + (size_t)l * NF * HC,
                                        att_src + (size_t)l * NH * CC,
                                        att_dst + (size_t)l * NH * CC,
                                        xpb, a_s, a_d);
    k_alpha<<<nbEN, 256, 0, stream>>>(esrc, edst, eattr, sl, a_s, a_d,
                                      We + (size_t)l * BF * HC,
                                      att_edge + (size_t)l * NH * CC,
                                      pos, alpha_csr, alpha_self);
    k_aggr<<<(NN + 3) / 4, 256, 0, stream>>>(xpb, alpha_csr, alpha_self,
                                             src_csr, offs, b + (size_t)l * HC, h_buf);
  }
  k_final<<<(NN + 63) / 64, 256, 0, stream>>>(x, h_buf, Wout, bout, out);
}

// Round 4
// 688.960 us; speedup vs baseline: 2.4497x; 1.1752x over previous
//
#include <hip/hip_runtime.h>

#define NN 50000
#define NE 800000
#define NF 128
#define BF 16
#define NH 4
#define HC 128
#define CC 32
#define DEPTH 5
#define NEG 0.2f

typedef __attribute__((ext_vector_type(8))) short bf16x8;
typedef __attribute__((ext_vector_type(4))) float f32x4;

__device__ inline unsigned short f2bf(float f) {
  union { float f; unsigned u; } v; v.f = f;
  unsigned r = v.u + 0x7fff + ((v.u >> 16) & 1);
  return (unsigned short)(r >> 16);
}
__device__ inline float bf2f(unsigned short u) {
  union { unsigned u; float f; } v; v.u = (unsigned)u << 16; return v.f;
}

// ---------------- CSR build ----------------
__global__ void k_count(const int* __restrict__ dst, int* __restrict__ deg) {
  int e = blockIdx.x * 256 + threadIdx.x;
  if (e < NE) atomicAdd(&deg[dst[e]], 1);
}

__global__ void k_partial(const int* __restrict__ deg, int* __restrict__ bsum) {
  __shared__ int s[256];
  int t = threadIdx.x;
  int i = blockIdx.x * 256 + t;
  s[t] = (i < NN) ? deg[i] : 0;
  __syncthreads();
  for (int d = 128; d > 0; d >>= 1) {
    if (t < d) s[t] += s[t + d];
    __syncthreads();
  }
  if (t == 0) bsum[blockIdx.x] = s[0];
}

__global__ void k_scan_top(int* __restrict__ bsum, int nb) {
  if (threadIdx.x == 0 && blockIdx.x == 0) {
    int run = 0;
    for (int i = 0; i < nb; ++i) { int v = bsum[i]; bsum[i] = run; run += v; }
  }
}

__global__ void k_scan_write(const int* __restrict__ deg, const int* __restrict__ bsum,
                             int* __restrict__ offs) {
  __shared__ int s[256];
  int t = threadIdx.x;
  int i = blockIdx.x * 256 + t;
  int v = (i < NN) ? deg[i] : 0;
  s[t] = v;
  __syncthreads();
  for (int d = 1; d < 256; d <<= 1) {
    int x = (t >= d) ? s[t - d] : 0;
    __syncthreads();
    s[t] += x;
    __syncthreads();
  }
  if (i < NN) offs[i] = bsum[blockIdx.x] + s[t] - v;
  if (i == 0) offs[NN] = NE;
}

__global__ void k_fill(const int* __restrict__ src, const int* __restrict__ dst,
                       const int* __restrict__ offs, int* __restrict__ cur,
                       int* __restrict__ csr, int* __restrict__ src_csr,
                       int* __restrict__ pos) {
  int e = blockIdx.x * 256 + threadIdx.x;
  if (e < NE) {
    int d = dst[e];
    int p = atomicAdd(&cur[d], 1);
    int slot = offs[d] + p;
    csr[slot] = e;
    src_csr[slot] = src[e];
    pos[e] = slot;
  }
}

__global__ void k_slattr(const int* __restrict__ offs, const int* __restrict__ csr,
                         const float* __restrict__ eattr, float* __restrict__ sl) {
  int idx = blockIdx.x * 256 + threadIdx.x; // NN*BF
  if (idx >= NN * BF) return;
  int n = idx >> 4, f = idx & 15;
  int s = offs[n], e = offs[n + 1];
  float acc = 0.f;
  for (int i = s; i < e; ++i) acc += eattr[(size_t)csr[i] * BF + f];
  int cnt = e - s;
  sl[idx] = acc / fmaxf((float)cnt, 1.0f);
}

// ---------------- prep: fp32 -> bf16 conversions ----------------
__global__ void k_x2bf(const float* __restrict__ x, unsigned short* __restrict__ xb) {
  int i = blockIdx.x * 256 + threadIdx.x; // NN*32 float4 quads
  if (i >= NN * 32) return;
  float4 v = ((const float4*)x)[i];
  ushort4 u;
  u.x = f2bf(v.x); u.y = f2bf(v.y); u.z = f2bf(v.z); u.w = f2bf(v.w);
  ((ushort4*)xb)[i] = u;
}

// Wt[l][n][k] = bf16(W[l][k][n])
__global__ void k_wprep(const float* __restrict__ W, unsigned short* __restrict__ Wt) {
  int idx = blockIdx.x * 256 + threadIdx.x; // DEPTH*128*128
  if (idx >= DEPTH * NF * HC) return;
  int l = idx >> 14;
  int rem = idx & 16383;
  int n = rem >> 7, k = rem & 127;
  Wt[(size_t)l * 16384 + (size_t)n * 128 + k] = f2bf(W[(size_t)l * 16384 + (size_t)k * 128 + n]);
}

// ---------------- per-layer kernels ----------------
// xp = A @ W via bf16 MFMA. A: [NN][128] bf16 row-major; Wt: [128][128] bf16 = W^T.
// Block: 64 rows x 128 cols, 4 waves; wave = 4 row-tiles x 2 col-tiles of 16x16.
__global__ __launch_bounds__(256) void k_gemm_mfma(const unsigned short* __restrict__ Ab,
                                                   const unsigned short* __restrict__ Wt,
                                                   unsigned short* __restrict__ xpb) {
  int t = threadIdx.x;
  int wv = t >> 6;        // wave: col group wv*32
  int l = t & 63;
  int r0 = blockIdx.x * 64;
  int lk = (l >> 4) * 8;  // k-offset within a 32-wide K step
  int c0 = wv * 32;
  f32x4 acc[4][2] = {};
#pragma unroll
  for (int ks = 0; ks < 4; ++ks) {
    int kb = ks * 32 + lk;
    bf16x8 bfr0 = *(const bf16x8*)&Wt[(size_t)(c0 + (l & 15)) * 128 + kb];
    bf16x8 bfr1 = *(const bf16x8*)&Wt[(size_t)(c0 + 16 + (l & 15)) * 128 + kb];
#pragma unroll
    for (int rt = 0; rt < 4; ++rt) {
      int row = r0 + rt * 16 + (l & 15);
      row = row < NN ? row : NN - 1;
      bf16x8 afr = *(const bf16x8*)&Ab[(size_t)row * 128 + kb];
      acc[rt][0] = __builtin_amdgcn_mfma_f32_16x16x32_bf16(afr, bfr0, acc[rt][0], 0, 0, 0);
      acc[rt][1] = __builtin_amdgcn_mfma_f32_16x16x32_bf16(afr, bfr1, acc[rt][1], 0, 0, 0);
    }
  }
  // C/D: col = lane&15, row = (lane>>4)*4 + reg
#pragma unroll
  for (int rt = 0; rt < 4; ++rt) {
#pragma unroll
    for (int ct = 0; ct < 2; ++ct) {
#pragma unroll
      for (int j = 0; j < 4; ++j) {
        int row = r0 + rt * 16 + (l >> 4) * 4 + j;
        int col = c0 + ct * 16 + (l & 15);
        if (row < NN) xpb[(size_t)row * 128 + col] = f2bf(acc[rt][ct][j]);
      }
    }
  }
}

// a_s[n,h] = xp[n,h,:]·att_src[h,:]; a_d likewise (bf16 xp input)
__global__ void k_asad(const unsigned short* __restrict__ xpb, const float* __restrict__ as_w,
                       const float* __restrict__ ad_w, float* __restrict__ a_s,
                       float* __restrict__ a_d) {
  int idx = blockIdx.x * 256 + threadIdx.x;
  if (idx >= NN * NH) return;
  int n = idx >> 2, h = idx & 3;
  const ushort4* xr = (const ushort4*)(xpb + (size_t)n * HC + h * CC);
  const float4* sw = (const float4*)(as_w + h * CC);
  const float4* dw = (const float4*)(ad_w + h * CC);
  float s = 0.f, d = 0.f;
#pragma unroll
  for (int i = 0; i < 8; ++i) {
    ushort4 xu = xr[i];
    float4 s4 = sw[i], d4 = dw[i];
    float x0 = bf2f(xu.x), x1 = bf2f(xu.y), x2 = bf2f(xu.z), x3 = bf2f(xu.w);
    s += x0 * s4.x + x1 * s4.y + x2 * s4.z + x3 * s4.w;
    d += x0 * d4.x + x1 * d4.y + x2 * d4.z + x3 * d4.w;
  }
  a_s[idx] = s;
  a_d[idx] = d;
}

// alpha = leaky_relu(a_s[src]+a_d[dst]+ea·we_eff); scatter into CSR order.
__global__ __launch_bounds__(256) void k_alpha(const int* __restrict__ esrc, const int* __restrict__ edst,
                                               const float* __restrict__ eattr, const float* __restrict__ sl,
                                               const float* __restrict__ a_s, const float* __restrict__ a_d,
                                               const float* __restrict__ We_l, const float* __restrict__ ae_l,
                                               const int* __restrict__ pos,
                                               float* __restrict__ alpha_csr,
                                               float* __restrict__ alpha_self) {
  __shared__ float weff[BF][NH];
  int t = threadIdx.x;
  if (t < BF * NH) {
    int f = t >> 2, h = t & 3;
    float acc = 0.f;
    for (int c = 0; c < CC; ++c) acc += We_l[f * HC + h * CC + c] * ae_l[h * CC + c];
    weff[f][h] = acc;
  }
  __syncthreads();
  int e = blockIdx.x * 256 + t;
  if (e >= NE + NN) return;
  int src, dst;
  const float* attr;
  if (e < NE) {
    src = esrc[e]; dst = edst[e]; attr = eattr + (size_t)e * BF;
  } else {
    src = dst = e - NE; attr = sl + (size_t)(e - NE) * BF;
  }
  float ae[NH] = {0.f, 0.f, 0.f, 0.f};
#pragma unroll
  for (int f = 0; f < BF; ++f) {
    float av = attr[f];
    ae[0] += av * weff[f][0]; ae[1] += av * weff[f][1];
    ae[2] += av * weff[f][2]; ae[3] += av * weff[f][3];
  }
  float4 sv = ((const float4*)a_s)[src];
  float4 dv = ((const float4*)a_d)[dst];
  float v0 = sv.x + dv.x + ae[0];
  float v1 = sv.y + dv.y + ae[1];
  float v2 = sv.z + dv.z + ae[2];
  float v3 = sv.w + dv.w + ae[3];
  float4 o;
  o.x = v0 > 0.f ? v0 : NEG * v0;
  o.y = v1 > 0.f ? v1 : NEG * v1;
  o.z = v2 > 0.f ? v2 : NEG * v2;
  o.w = v3 > 0.f ? v3 : NEG * v3;
  if (e < NE)
    ((float4*)alpha_csr)[pos[e]] = o;
  else
    ((float4*)alpha_self)[e - NE] = o;
}

// one wave per node: online softmax + aggregate (bf16 xp gather), streamed CSR.
// lane owns channels {2*lane, 2*lane+1}; head = lane>>4. Output h in bf16.
__global__ __launch_bounds__(256) void k_aggr(const unsigned short* __restrict__ xpb,
                                              const float* __restrict__ alpha_csr,
                                              const float* __restrict__ alpha_self,
                                              const int* __restrict__ src_csr,
                                              const int* __restrict__ offs,
                                              const float* __restrict__ b_l,
                                              unsigned short* __restrict__ hout) {
  int node = blockIdx.x * 4 + (threadIdx.x >> 6);
  if (node >= NN) return;
  int lane = threadIdx.x & 63;
  int h = lane >> 4;
  const ushort2* xp2 = (const ushort2*)xpb;
  int s = offs[node], e = offs[node + 1];
  float m = alpha_self[(size_t)node * 4 + h];
  ushort2 xs = xp2[(size_t)node * 64 + lane];
  float acc0 = bf2f(xs.x), acc1 = bf2f(xs.y);
  float den = 1.f;
  int i = s;
  for (; i + 4 <= e; i += 4) {
    int s0 = src_csr[i], s1 = src_csr[i + 1], s2 = src_csr[i + 2], s3 = src_csr[i + 3];
    float a0 = alpha_csr[(size_t)i * 4 + h];
    float a1 = alpha_csr[(size_t)(i + 1) * 4 + h];
    float a2 = alpha_csr[(size_t)(i + 2) * 4 + h];
    float a3 = alpha_csr[(size_t)(i + 3) * 4 + h];
    ushort2 x0 = xp2[(size_t)s0 * 64 + lane];
    ushort2 x1 = xp2[(size_t)s1 * 64 + lane];
    ushort2 x2 = xp2[(size_t)s2 * 64 + lane];
    ushort2 x3 = xp2[(size_t)s3 * 64 + lane];
    float mn = fmaxf(fmaxf(fmaxf(a0, a1), fmaxf(a2, a3)), m);
    float sc = __expf(m - mn);
    acc0 *= sc; acc1 *= sc; den *= sc; m = mn;
    float e0 = __expf(a0 - m), e1 = __expf(a1 - m), e2 = __expf(a2 - m), e3 = __expf(a3 - m);
    den += e0 + e1 + e2 + e3;
    acc0 += e0 * bf2f(x0.x) + e1 * bf2f(x1.x) + e2 * bf2f(x2.x) + e3 * bf2f(x3.x);
    acc1 += e0 * bf2f(x0.y) + e1 * bf2f(x1.y) + e2 * bf2f(x2.y) + e3 * bf2f(x3.y);
  }
  for (; i < e; ++i) {
    int s0 = src_csr[i];
    float a0 = alpha_csr[(size_t)i * 4 + h];
    ushort2 x0 = xp2[(size_t)s0 * 64 + lane];
    if (a0 > m) { float sc = __expf(m - a0); acc0 *= sc; acc1 *= sc; den *= sc; m = a0; }
    float e0 = __expf(a0 - m);
    den += e0;
    acc0 += e0 * bf2f(x0.x);
    acc1 += e0 * bf2f(x0.y);
  }
  float2 b2 = ((const float2*)b_l)[lane];
  float inv = 1.0f / (den + 1e-16f);
  float o0 = fmaxf(acc0 * inv + b2.x, 0.f);
  float o1 = fmaxf(acc1 * inv + b2.y, 0.f);
  ushort2 ho;
  ho.x = f2bf(o0); ho.y = f2bf(o1);
  ((ushort2*)hout)[(size_t)node * 64 + lane] = ho;
}

// out = relu([x, h] @ Wout + bout) — LDS-staged Wout; h is bf16.
__global__ __launch_bounds__(256) void k_final(const float* __restrict__ x,
                                               const unsigned short* __restrict__ h,
                                               const float* __restrict__ Wout, const float* __restrict__ bout,
                                               float* __restrict__ out) {
  __shared__ float4 wlds[2048]; // 256 x 32 fp32 = 32KB
  int t = threadIdx.x;
#pragma unroll
  for (int i = 0; i < 8; ++i) wlds[t + i * 256] = ((const float4*)Wout)[t + i * 256];
  __syncthreads();
  int tx = t & 7;   // col quad
  int ty = t >> 3;  // node within block (0..31); also ty+32
  int row0 = blockIdx.x * 64 + ty;
  int row1 = row0 + 32;
  bool v0 = row0 < NN, v1 = row1 < NN;
  const float4* x4 = (const float4*)x;
  const ushort4* h4 = (const ushort4*)h;
  float acc[2][4] = {};
  const float4 z = make_float4(0.f, 0.f, 0.f, 0.f);
#pragma unroll 4
  for (int k4 = 0; k4 < 32; ++k4) {
    float4 a0 = v0 ? x4[(size_t)row0 * 32 + k4] : z;
    float4 a1 = v1 ? x4[(size_t)row1 * 32 + k4] : z;
    float av0[4] = {a0.x, a0.y, a0.z, a0.w};
    float av1[4] = {a1.x, a1.y, a1.z, a1.w};
#pragma unroll
    for (int kk = 0; kk < 4; ++kk) {
      float4 w = wlds[(k4 * 4 + kk) * 8 + tx];
      acc[0][0] += av0[kk] * w.x; acc[0][1] += av0[kk] * w.y;
      acc[0][2] += av0[kk] * w.z; acc[0][3] += av0[kk] * w.w;
      acc[1][0] += av1[kk] * w.x; acc[1][1] += av1[kk] * w.y;
      acc[1][2] += av1[kk] * w.z; acc[1][3] += av1[kk] * w.w;
    }
  }
#pragma unroll 4
  for (int k4 = 0; k4 < 32; ++k4) {
    ushort4 u0 = v0 ? h4[(size_t)row0 * 32 + k4] : make_ushort4(0, 0, 0, 0);
    ushort4 u1 = v1 ? h4[(size_t)row1 * 32 + k4] : make_ushort4(0, 0, 0, 0);
    float av0[4] = {bf2f(u0.x), bf2f(u0.y), bf2f(u0.z), bf2f(u0.w)};
    float av1[4] = {bf2f(u1.x), bf2f(u1.y), bf2f(u1.z), bf2f(u1.w)};
#pragma unroll
    for (int kk = 0; kk < 4; ++kk) {
      float4 w = wlds[(128 + k4 * 4 + kk) * 8 + tx];
      acc[0][0] += av0[kk] * w.x; acc[0][1] += av0[kk] * w.y;
      acc[0][2] += av0[kk] * w.z; acc[0][3] += av0[kk] * w.w;
      acc[1][0] += av1[kk] * w.x; acc[1][1] += av1[kk] * w.y;
      acc[1][2] += av1[kk] * w.z; acc[1][3] += av1[kk] * w.w;
    }
  }
  float4 b4 = ((const float4*)bout)[tx];
  if (v0) {
    float4 o = make_float4(fmaxf(acc[0][0] + b4.x, 0.f), fmaxf(acc[0][1] + b4.y, 0.f),
                           fmaxf(acc[0][2] + b4.z, 0.f), fmaxf(acc[0][3] + b4.w, 0.f));
    ((float4*)out)[(size_t)row0 * 8 + tx] = o;
  }
  if (v1) {
    float4 o = make_float4(fmaxf(acc[1][0] + b4.x, 0.f), fmaxf(acc[1][1] + b4.y, 0.f),
                           fmaxf(acc[1][2] + b4.z, 0.f), fmaxf(acc[1][3] + b4.w, 0.f));
    ((float4*)out)[(size_t)row1 * 8 + tx] = o;
  }
}

extern "C" void kernel_launch(void* const* d_in, const int* in_sizes, int n_in,
                              void* d_out, int out_size, void* d_ws, size_t ws_size,
                              hipStream_t stream) {
  const float* x        = (const float*)d_in[0];
  const int*   eidx     = (const int*)d_in[1];
  const float* eattr    = (const float*)d_in[2];
  const float* W        = (const float*)d_in[3];
  const float* att_src  = (const float*)d_in[4];
  const float* att_dst  = (const float*)d_in[5];
  const float* We       = (const float*)d_in[6];
  const float* att_edge = (const float*)d_in[7];
  const float* b        = (const float*)d_in[8];
  const float* Wout     = (const float*)d_in[9];
  const float* bout     = (const float*)d_in[10];
  float* out = (float*)d_out;

  const int* esrc = eidx;
  const int* edst = eidx + NE;

  size_t off = 0;
  auto carve = [&](size_t bytes) {
    void* p = (char*)d_ws + off;
    off += (bytes + 255) & ~(size_t)255;
    return p;
  };
  unsigned short* h_buf = (unsigned short*)carve((size_t)NN * HC * 2);
  unsigned short* x_bf  = (unsigned short*)carve((size_t)NN * NF * 2);
  unsigned short* xpb   = (unsigned short*)carve((size_t)NN * HC * 2);
  unsigned short* Wt    = (unsigned short*)carve((size_t)DEPTH * NF * HC * 2);
  float* a_s    = (float*)carve((size_t)NN * NH * 4);
  float* a_d    = (float*)carve((size_t)NN * NH * 4);
  float* alpha_csr  = (float*)carve((size_t)NE * NH * 4);
  float* alpha_self = (float*)carve((size_t)NN * NH * 4);
  float* sl     = (float*)carve((size_t)NN * BF * 4);
  int* deg  = (int*)carve((size_t)NN * 4);
  int* offs = (int*)carve((size_t)(NN + 1) * 4);
  int* cur  = (int*)carve((size_t)NN * 4);
  int* csr  = (int*)carve((size_t)NE * 4);
  int* src_csr = (int*)carve((size_t)NE * 4);
  int* pos  = (int*)carve((size_t)NE * 4);
  int* bsum = (int*)carve(1024);

  const int nbN = (NN + 255) / 256;
  const int nbE = (NE + 255) / 256;
  const int nbEN = (NE + NN + 255) / 256;

  hipMemsetAsync(deg, 0, (size_t)NN * 4, stream);
  hipMemsetAsync(cur, 0, (size_t)NN * 4, stream);
  k_count<<<nbE, 256, 0, stream>>>(edst, deg);
  k_partial<<<nbN, 256, 0, stream>>>(deg, bsum);
  k_scan_top<<<1, 64, 0, stream>>>(bsum, nbN);
  k_scan_write<<<nbN, 256, 0, stream>>>(deg, bsum, offs);
  k_fill<<<nbE, 256, 0, stream>>>(esrc, edst, offs, cur, csr, src_csr, pos);
  k_slattr<<<(NN * BF + 255) / 256, 256, 0, stream>>>(offs, csr, eattr, sl);
  k_x2bf<<<(NN * 32 + 255) / 256, 256, 0, stream>>>(x, x_bf);
  k_wprep<<<(DEPTH * NF * HC + 255) / 256, 256, 0, stream>>>(W, Wt);

  for (int l = 0; l < DEPTH; ++l) {
    const unsigned short* A = (l == 0) ? x_bf : h_buf;
    k_gemm_mfma<<<(NN + 63) / 64, 256, 0, stream>>>(A, Wt + (size_t)l * NF * HC, xpb);
    k_asad<<<(NN * NH + 255) / 256, 256, 0, stream>>>(xpb, att_src + (size_t)l * NH * CC,
                                                      att_dst + (size_t)l * NH * CC, a_s, a_d);
    k_alpha<<<nbEN, 256, 0, stream>>>(esrc, edst, eattr, sl, a_s, a_d,
                                      We + (size_t)l * BF * HC,
                                      att_edge + (size_t)l * NH * CC,
                                      pos, alpha_csr, alpha_self);
    k_aggr<<<(NN + 3) / 4, 256, 0, stream>>>(xpb, alpha_csr, alpha_self,
                                             src_csr, offs, b + (size_t)l * HC, h_buf);
  }
  k_final<<<(NN + 63) / 64, 256, 0, stream>>>(x, h_buf, Wout, bout, out);
}

// Round 5
// 534.796 us; speedup vs baseline: 3.1559x; 1.2883x over previous
//
#include <hip/hip_runtime.h>

#define NN 50000
#define NE 800000
#define NF 128
#define BF 16
#define NH 4
#define HC 128
#define CC 32
#define DEPTH 5
#define NEG 0.2f

typedef __attribute__((ext_vector_type(8))) short bf16x8;
typedef __attribute__((ext_vector_type(4))) float f32x4;

__device__ inline unsigned short f2bf(float f) {
  union { float f; unsigned u; } v; v.f = f;
  unsigned r = v.u + 0x7fff + ((v.u >> 16) & 1);
  return (unsigned short)(r >> 16);
}
__device__ inline float bf2f(unsigned short u) {
  union { unsigned u; float f; } v; v.u = (unsigned)u << 16; return v.f;
}

// ---------------- CSR build ----------------
__global__ void k_count(const int* __restrict__ dst, int* __restrict__ deg) {
  int e = blockIdx.x * 256 + threadIdx.x;
  if (e < NE) atomicAdd(&deg[dst[e]], 1);
}

__global__ void k_partial(const int* __restrict__ deg, int* __restrict__ bsum) {
  __shared__ int s[256];
  int t = threadIdx.x;
  int i = blockIdx.x * 256 + t;
  s[t] = (i < NN) ? deg[i] : 0;
  __syncthreads();
  for (int d = 128; d > 0; d >>= 1) {
    if (t < d) s[t] += s[t + d];
    __syncthreads();
  }
  if (t == 0) bsum[blockIdx.x] = s[0];
}

__global__ void k_scan_top(int* __restrict__ bsum, int nb) {
  if (threadIdx.x == 0 && blockIdx.x == 0) {
    int run = 0;
    for (int i = 0; i < nb; ++i) { int v = bsum[i]; bsum[i] = run; run += v; }
  }
}

__global__ void k_scan_write(const int* __restrict__ deg, const int* __restrict__ bsum,
                             int* __restrict__ offs) {
  __shared__ int s[256];
  int t = threadIdx.x;
  int i = blockIdx.x * 256 + t;
  int v = (i < NN) ? deg[i] : 0;
  s[t] = v;
  __syncthreads();
  for (int d = 1; d < 256; d <<= 1) {
    int x = (t >= d) ? s[t - d] : 0;
    __syncthreads();
    s[t] += x;
    __syncthreads();
  }
  if (i < NN) offs[i] = bsum[blockIdx.x] + s[t] - v;
  if (i == 0) offs[NN] = NE;
}

// single int2 scatter per edge: (eid, src)
__global__ void k_fill(const int* __restrict__ src, const int* __restrict__ dst,
                       const int* __restrict__ offs, int* __restrict__ cur,
                       int2* __restrict__ csr2) {
  int e = blockIdx.x * 256 + threadIdx.x;
  if (e < NE) {
    int d = dst[e];
    int p = atomicAdd(&cur[d], 1);
    csr2[offs[d] + p] = make_int2(e, src[e]);
  }
}

// ---------------- prep kernels (once) ----------------
// weff[l][f][h] = sum_c We[l][f][h*32+c] * att_edge[l][h][c]
__global__ void k_weff(const float* __restrict__ We, const float* __restrict__ ae,
                       float* __restrict__ weff) {
  int idx = threadIdx.x;
  if (idx >= DEPTH * BF * NH) return;
  int l = idx / (BF * NH);
  int r = idx - l * (BF * NH);
  int f = r >> 2, h = r & 3;
  const float* We_l = We + (size_t)l * BF * HC;
  const float* ae_l = ae + (size_t)l * NH * CC;
  float acc = 0.f;
  for (int c = 0; c < CC; ++c) acc += We_l[f * HC + h * CC + c] * ae_l[h * CC + c];
  weff[idx] = acc;
}

// per CSR slot: a_e for all layers/heads, bf16, coalesced. ae_csr layout: [l][NE] ushort4
__global__ __launch_bounds__(256) void k_aeprep(const int2* __restrict__ csr2,
                                                const float* __restrict__ eattr,
                                                const float* __restrict__ weff,
                                                unsigned short* __restrict__ ae_csr) {
  __shared__ float sw[DEPTH * BF * NH];
  int t = threadIdx.x;
  if (t < DEPTH * BF * NH) sw[t] = weff[t];
  __syncthreads();
  int i = blockIdx.x * 256 + t;
  if (i >= NE) return;
  int eid = csr2[i].x;
  float at[16];
  const float4* ar = (const float4*)(eattr + (size_t)eid * BF);
#pragma unroll
  for (int q = 0; q < 4; ++q) {
    float4 v = ar[q];
    at[q * 4] = v.x; at[q * 4 + 1] = v.y; at[q * 4 + 2] = v.z; at[q * 4 + 3] = v.w;
  }
#pragma unroll
  for (int l = 0; l < DEPTH; ++l) {
    float a0 = 0.f, a1 = 0.f, a2 = 0.f, a3 = 0.f;
#pragma unroll
    for (int f = 0; f < BF; ++f) {
      float av = at[f];
      const float* wf = &sw[(l * BF + f) * NH];
      a0 += av * wf[0]; a1 += av * wf[1]; a2 += av * wf[2]; a3 += av * wf[3];
    }
    ushort4 u;
    u.x = f2bf(a0); u.y = f2bf(a1); u.z = f2bf(a2); u.w = f2bf(a3);
    ((ushort4*)ae_csr)[(size_t)l * NE + i] = u;
  }
}

// self-loop a_e = mean over incoming edges of per-edge a_e (linearity)
__global__ void k_aeself(const unsigned short* __restrict__ ae_csr,
                         const int* __restrict__ offs,
                         unsigned short* __restrict__ ae_self) {
  int idx = blockIdx.x * 256 + threadIdx.x;
  if (idx >= NN * DEPTH) return;
  int l = idx / NN, n = idx - l * NN;
  int s = offs[n], e = offs[n + 1];
  const ushort4* base = (const ushort4*)ae_csr + (size_t)l * NE;
  float a0 = 0.f, a1 = 0.f, a2 = 0.f, a3 = 0.f;
  for (int i = s; i < e; ++i) {
    ushort4 u = base[i];
    a0 += bf2f(u.x); a1 += bf2f(u.y); a2 += bf2f(u.z); a3 += bf2f(u.w);
  }
  float inv = 1.0f / fmaxf((float)(e - s), 1.0f);
  ushort4 o;
  o.x = f2bf(a0 * inv); o.y = f2bf(a1 * inv); o.z = f2bf(a2 * inv); o.w = f2bf(a3 * inv);
  ((ushort4*)ae_self)[(size_t)l * NN + n] = o;
}

// fp32 -> bf16 for x (into h_buf, which doubles as layer-0 input)
__global__ void k_x2bf(const float* __restrict__ x, unsigned short* __restrict__ xb) {
  int i = blockIdx.x * 256 + threadIdx.x; // NN*32 float4 quads
  if (i >= NN * 32) return;
  float4 v = ((const float4*)x)[i];
  ushort4 u;
  u.x = f2bf(v.x); u.y = f2bf(v.y); u.z = f2bf(v.z); u.w = f2bf(v.w);
  ((ushort4*)xb)[i] = u;
}

// Wt[l][n][k] = bf16(W[l][k][n])
__global__ void k_wprep(const float* __restrict__ W, unsigned short* __restrict__ Wt) {
  int idx = blockIdx.x * 256 + threadIdx.x;
  if (idx >= DEPTH * NF * HC) return;
  int l = idx >> 14;
  int rem = idx & 16383;
  int n = rem >> 7, k = rem & 127;
  Wt[(size_t)l * 16384 + (size_t)n * 128 + k] = f2bf(W[(size_t)l * 16384 + (size_t)k * 128 + n]);
}

// ---------------- per-layer kernels ----------------
// xp = A @ W via bf16 MFMA + fused a_s/a_d epilogue.
// Block: 64 rows x 128 cols, 4 waves; wave wv owns cols wv*32..wv*32+31 == head wv.
__global__ __launch_bounds__(256) void k_gemm_mfma(const unsigned short* __restrict__ Ab,
                                                   const unsigned short* __restrict__ Wt,
                                                   const float* __restrict__ as_w,
                                                   const float* __restrict__ ad_w,
                                                   unsigned short* __restrict__ xpb,
                                                   float* __restrict__ a_s,
                                                   float* __restrict__ a_d) {
  int t = threadIdx.x;
  int wv = t >> 6;
  int l = t & 63;
  int r0 = blockIdx.x * 64;
  int lk = (l >> 4) * 8;
  int c0 = wv * 32;
  f32x4 acc[4][2] = {};
#pragma unroll
  for (int ks = 0; ks < 4; ++ks) {
    int kb = ks * 32 + lk;
    bf16x8 bfr0 = *(const bf16x8*)&Wt[(size_t)(c0 + (l & 15)) * 128 + kb];
    bf16x8 bfr1 = *(const bf16x8*)&Wt[(size_t)(c0 + 16 + (l & 15)) * 128 + kb];
#pragma unroll
    for (int rt = 0; rt < 4; ++rt) {
      int row = r0 + rt * 16 + (l & 15);
      row = row < NN ? row : NN - 1;
      bf16x8 afr = *(const bf16x8*)&Ab[(size_t)row * 128 + kb];
      acc[rt][0] = __builtin_amdgcn_mfma_f32_16x16x32_bf16(afr, bfr0, acc[rt][0], 0, 0, 0);
      acc[rt][1] = __builtin_amdgcn_mfma_f32_16x16x32_bf16(afr, bfr1, acc[rt][1], 0, 0, 0);
    }
  }
  // per-lane att weights for its two cols within head wv
  float asv0 = as_w[c0 + (l & 15)], asv1 = as_w[c0 + 16 + (l & 15)];
  float adv0 = ad_w[c0 + (l & 15)], adv1 = ad_w[c0 + 16 + (l & 15)];
  // C/D: col = lane&15, row = (lane>>4)*4 + reg
#pragma unroll
  for (int rt = 0; rt < 4; ++rt) {
#pragma unroll
    for (int j = 0; j < 4; ++j) {
      int row = r0 + rt * 16 + (l >> 4) * 4 + j;
      float c0v = acc[rt][0][j], c1v = acc[rt][1][j];
      if (row < NN) {
        xpb[(size_t)row * 128 + c0 + (l & 15)] = f2bf(c0v);
        xpb[(size_t)row * 128 + c0 + 16 + (l & 15)] = f2bf(c1v);
      }
      float ps = c0v * asv0 + c1v * asv1;
      float pd = c0v * adv0 + c1v * adv1;
      ps += __shfl_xor(ps, 1); pd += __shfl_xor(pd, 1);
      ps += __shfl_xor(ps, 2); pd += __shfl_xor(pd, 2);
      ps += __shfl_xor(ps, 4); pd += __shfl_xor(pd, 4);
      ps += __shfl_xor(ps, 8); pd += __shfl_xor(pd, 8);
      if ((l & 15) == 0 && row < NN) {
        a_s[(size_t)row * 4 + wv] = ps;
        a_d[(size_t)row * 4 + wv] = pd;
      }
    }
  }
}

// one wave per node: alpha computed inline, online softmax, bf16 xp gather.
// lane owns channels {2*lane, 2*lane+1}; head h = lane>>4.
__global__ __launch_bounds__(256) void k_aggr(const unsigned short* __restrict__ xpb,
                                              const unsigned short* __restrict__ ae_l,
                                              const unsigned short* __restrict__ aeself_l,
                                              const float* __restrict__ a_s,
                                              const float* __restrict__ a_d,
                                              const int2* __restrict__ csr2,
                                              const int* __restrict__ offs,
                                              const float* __restrict__ b_l,
                                              unsigned short* __restrict__ hout) {
  int node = blockIdx.x * 4 + (threadIdx.x >> 6);
  if (node >= NN) return;
  int lane = threadIdx.x & 63;
  int h = lane >> 4;
  const ushort2* xp2 = (const ushort2*)xpb;
  int s = offs[node], e = offs[node + 1];
  float ad = a_d[(size_t)node * 4 + h];
  float vs = a_s[(size_t)node * 4 + h] + ad + bf2f(aeself_l[(size_t)node * 4 + h]);
  vs = vs > 0.f ? vs : NEG * vs;
  float m = vs;
  ushort2 xs = xp2[(size_t)node * 64 + lane];
  float acc0 = bf2f(xs.x), acc1 = bf2f(xs.y);  // self: exp(vs - m) = 1
  float den = 1.f;
  int i = s;
  for (; i + 4 <= e; i += 4) {
    int s0 = csr2[i].y, s1 = csr2[i + 1].y, s2 = csr2[i + 2].y, s3 = csr2[i + 3].y;
    float a0 = a_s[(size_t)s0 * 4 + h] + ad + bf2f(ae_l[(size_t)i * 4 + h]);
    float a1 = a_s[(size_t)s1 * 4 + h] + ad + bf2f(ae_l[(size_t)(i + 1) * 4 + h]);
    float a2 = a_s[(size_t)s2 * 4 + h] + ad + bf2f(ae_l[(size_t)(i + 2) * 4 + h]);
    float a3 = a_s[(size_t)s3 * 4 + h] + ad + bf2f(ae_l[(size_t)(i + 3) * 4 + h]);
    a0 = a0 > 0.f ? a0 : NEG * a0;
    a1 = a1 > 0.f ? a1 : NEG * a1;
    a2 = a2 > 0.f ? a2 : NEG * a2;
    a3 = a3 > 0.f ? a3 : NEG * a3;
    ushort2 x0 = xp2[(size_t)s0 * 64 + lane];
    ushort2 x1 = xp2[(size_t)s1 * 64 + lane];
    ushort2 x2 = xp2[(size_t)s2 * 64 + lane];
    ushort2 x3 = xp2[(size_t)s3 * 64 + lane];
    float mn = fmaxf(fmaxf(fmaxf(a0, a1), fmaxf(a2, a3)), m);
    float sc = __expf(m - mn);
    acc0 *= sc; acc1 *= sc; den *= sc; m = mn;
    float e0 = __expf(a0 - m), e1 = __expf(a1 - m), e2 = __expf(a2 - m), e3 = __expf(a3 - m);
    den += e0 + e1 + e2 + e3;
    acc0 += e0 * bf2f(x0.x) + e1 * bf2f(x1.x) + e2 * bf2f(x2.x) + e3 * bf2f(x3.x);
    acc1 += e0 * bf2f(x0.y) + e1 * bf2f(x1.y) + e2 * bf2f(x2.y) + e3 * bf2f(x3.y);
  }
  for (; i < e; ++i) {
    int s0 = csr2[i].y;
    float a0 = a_s[(size_t)s0 * 4 + h] + ad + bf2f(ae_l[(size_t)i * 4 + h]);
    a0 = a0 > 0.f ? a0 : NEG * a0;
    ushort2 x0 = xp2[(size_t)s0 * 64 + lane];
    if (a0 > m) { float sc = __expf(m - a0); acc0 *= sc; acc1 *= sc; den *= sc; m = a0; }
    float e0 = __expf(a0 - m);
    den += e0;
    acc0 += e0 * bf2f(x0.x);
    acc1 += e0 * bf2f(x0.y);
  }
  float2 b2 = ((const float2*)b_l)[lane];
  float inv = 1.0f / (den + 1e-16f);
  float o0 = fmaxf(acc0 * inv + b2.x, 0.f);
  float o1 = fmaxf(acc1 * inv + b2.y, 0.f);
  ushort2 ho;
  ho.x = f2bf(o0); ho.y = f2bf(o1);
  ((ushort2*)hout)[(size_t)node * 64 + lane] = ho;
}

// out = relu([x, h] @ Wout + bout) — LDS-staged Wout; h is bf16.
__global__ __launch_bounds__(256) void k_final(const float* __restrict__ x,
                                               const unsigned short* __restrict__ h,
                                               const float* __restrict__ Wout, const float* __restrict__ bout,
                                               float* __restrict__ out) {
  __shared__ float4 wlds[2048]; // 256 x 32 fp32 = 32KB
  int t = threadIdx.x;
#pragma unroll
  for (int i = 0; i < 8; ++i) wlds[t + i * 256] = ((const float4*)Wout)[t + i * 256];
  __syncthreads();
  int tx = t & 7;
  int ty = t >> 3;
  int row0 = blockIdx.x * 64 + ty;
  int row1 = row0 + 32;
  bool v0 = row0 < NN, v1 = row1 < NN;
  const float4* x4 = (const float4*)x;
  const ushort4* h4 = (const ushort4*)h;
  float acc[2][4] = {};
  const float4 z = make_float4(0.f, 0.f, 0.f, 0.f);
#pragma unroll 4
  for (int k4 = 0; k4 < 32; ++k4) {
    float4 a0 = v0 ? x4[(size_t)row0 * 32 + k4] : z;
    float4 a1 = v1 ? x4[(size_t)row1 * 32 + k4] : z;
    float av0[4] = {a0.x, a0.y, a0.z, a0.w};
    float av1[4] = {a1.x, a1.y, a1.z, a1.w};
#pragma unroll
    for (int kk = 0; kk < 4; ++kk) {
      float4 w = wlds[(k4 * 4 + kk) * 8 + tx];
      acc[0][0] += av0[kk] * w.x; acc[0][1] += av0[kk] * w.y;
      acc[0][2] += av0[kk] * w.z; acc[0][3] += av0[kk] * w.w;
      acc[1][0] += av1[kk] * w.x; acc[1][1] += av1[kk] * w.y;
      acc[1][2] += av1[kk] * w.z; acc[1][3] += av1[kk] * w.w;
    }
  }
#pragma unroll 4
  for (int k4 = 0; k4 < 32; ++k4) {
    ushort4 u0 = v0 ? h4[(size_t)row0 * 32 + k4] : make_ushort4(0, 0, 0, 0);
    ushort4 u1 = v1 ? h4[(size_t)row1 * 32 + k4] : make_ushort4(0, 0, 0, 0);
    float av0[4] = {bf2f(u0.x), bf2f(u0.y), bf2f(u0.z), bf2f(u0.w)};
    float av1[4] = {bf2f(u1.x), bf2f(u1.y), bf2f(u1.z), bf2f(u1.w)};
#pragma unroll
    for (int kk = 0; kk < 4; ++kk) {
      float4 w = wlds[(128 + k4 * 4 + kk) * 8 + tx];
      acc[0][0] += av0[kk] * w.x; acc[0][1] += av0[kk] * w.y;
      acc[0][2] += av0[kk] * w.z; acc[0][3] += av0[kk] * w.w;
      acc[1][0] += av1[kk] * w.x; acc[1][1] += av1[kk] * w.y;
      acc[1][2] += av1[kk] * w.z; acc[1][3] += av1[kk] * w.w;
    }
  }
  float4 b4 = ((const float4*)bout)[tx];
  if (v0) {
    float4 o = make_float4(fmaxf(acc[0][0] + b4.x, 0.f), fmaxf(acc[0][1] + b4.y, 0.f),
                           fmaxf(acc[0][2] + b4.z, 0.f), fmaxf(acc[0][3] + b4.w, 0.f));
    ((float4*)out)[(size_t)row0 * 8 + tx] = o;
  }
  if (v1) {
    float4 o = make_float4(fmaxf(acc[1][0] + b4.x, 0.f), fmaxf(acc[1][1] + b4.y, 0.f),
                           fmaxf(acc[1][2] + b4.z, 0.f), fmaxf(acc[1][3] + b4.w, 0.f));
    ((float4*)out)[(size_t)row1 * 8 + tx] = o;
  }
}

extern "C" void kernel_launch(void* const* d_in, const int* in_sizes, int n_in,
                              void* d_out, int out_size, void* d_ws, size_t ws_size,
                              hipStream_t stream) {
  const float* x        = (const float*)d_in[0];
  const int*   eidx     = (const int*)d_in[1];
  const float* eattr    = (const float*)d_in[2];
  const float* W        = (const float*)d_in[3];
  const float* att_src  = (const float*)d_in[4];
  const float* att_dst  = (const float*)d_in[5];
  const float* We       = (const float*)d_in[6];
  const float* att_edge = (const float*)d_in[7];
  const float* b        = (const float*)d_in[8];
  const float* Wout     = (const float*)d_in[9];
  const float* bout     = (const float*)d_in[10];
  float* out = (float*)d_out;

  const int* esrc = eidx;
  const int* edst = eidx + NE;

  size_t off = 0;
  auto carve = [&](size_t bytes) {
    void* p = (char*)d_ws + off;
    off += (bytes + 255) & ~(size_t)255;
    return p;
  };
  unsigned short* h_buf   = (unsigned short*)carve((size_t)NN * HC * 2);  // also holds bf16(x) for layer 0
  unsigned short* xpb     = (unsigned short*)carve((size_t)NN * HC * 2);
  unsigned short* Wt      = (unsigned short*)carve((size_t)DEPTH * NF * HC * 2);
  unsigned short* ae_csr  = (unsigned short*)carve((size_t)DEPTH * NE * NH * 2);
  unsigned short* ae_self = (unsigned short*)carve((size_t)DEPTH * NN * NH * 2);
  float* a_s   = (float*)carve((size_t)NN * NH * 4);
  float* a_d   = (float*)carve((size_t)NN * NH * 4);
  float* weff  = (float*)carve((size_t)DEPTH * BF * NH * 4);
  int* deg  = (int*)carve((size_t)NN * 4);
  int* offs = (int*)carve((size_t)(NN + 1) * 4);
  int* cur  = (int*)carve((size_t)NN * 4);
  int2* csr2 = (int2*)carve((size_t)NE * 8);
  int* bsum = (int*)carve(1024);

  const int nbN = (NN + 255) / 256;
  const int nbE = (NE + 255) / 256;

  hipMemsetAsync(deg, 0, (size_t)NN * 4, stream);
  hipMemsetAsync(cur, 0, (size_t)NN * 4, stream);
  k_count<<<nbE, 256, 0, stream>>>(edst, deg);
  k_partial<<<nbN, 256, 0, stream>>>(deg, bsum);
  k_scan_top<<<1, 64, 0, stream>>>(bsum, nbN);
  k_scan_write<<<nbN, 256, 0, stream>>>(deg, bsum, offs);
  k_fill<<<nbE, 256, 0, stream>>>(esrc, edst, offs, cur, csr2);
  k_weff<<<1, 320, 0, stream>>>(We, att_edge, weff);
  k_aeprep<<<nbE, 256, 0, stream>>>(csr2, eattr, weff, ae_csr);
  k_aeself<<<(NN * DEPTH + 255) / 256, 256, 0, stream>>>(ae_csr, offs, ae_self);
  k_x2bf<<<(NN * 32 + 255) / 256, 256, 0, stream>>>(x, h_buf);
  k_wprep<<<(DEPTH * NF * HC + 255) / 256, 256, 0, stream>>>(W, Wt);

  for (int l = 0; l < DEPTH; ++l) {
    k_gemm_mfma<<<(NN + 63) / 64, 256, 0, stream>>>(h_buf, Wt + (size_t)l * NF * HC,
                                                    att_src + (size_t)l * NH * CC,
                                                    att_dst + (size_t)l * NH * CC,
                                                    xpb, a_s, a_d);
    k_aggr<<<(NN + 3) / 4, 256, 0, stream>>>(xpb,
                                             ae_csr + (size_t)l * NE * NH,
                                             ae_self + (size_t)l * NN * NH,
                                             a_s, a_d, csr2, offs,
                                             b + (size_t)l * HC, h_buf);
  }
  k_final<<<(NN + 63) / 64, 256, 0, stream>>>(x, h_buf, Wout, bout, out);
}